// Round 17
// baseline (187.430 us; speedup 1.0000x reference)
//
#include <hip/hip_runtime.h>
#include <hip/hip_fp16.h>

// ---------------------------------------------------------------------------
// ClassificationKNNLoss on MI355X — R17: mega-kernel, 16 waves/CU, no VGPR cap.
//   k_prep : norms + bf16 convert with granule-XOR swizzle (+ zeroes d_out)
//   k_mega : 256 blocks (1/CU) x 1024 thr (16 waves). Block = 32 rows x ALL
//            8192 cols. B direct from global (L2-hot; no write stream). Zero
//            main-loop barriers/LDS. In-block merge (no k_fin).
// R14/R16 lesson (TOOLCHAIN): __launch_bounds__(B, w) caps VGPR at 256/w.
// (.,4) -> 64-VGPR cap -> spills (WRITE 73MB). This kernel needs ~108 VGPR,
// so use (1024, 2): cap 128; HW still gives 4 waves/SIMD at <=128 VGPR, so
// the whole 16-wave block is resident. R13 traffic (FETCH 16.8MB) preserved.
// ---------------------------------------------------------------------------

typedef __attribute__((ext_vector_type(8))) short s8v;       // 8 x bf16 (4 VGPR)
typedef __attribute__((ext_vector_type(4))) float f32x4;     // MFMA acc

#define NK 256

template <bool B> struct BoolC { static constexpr bool value = B; };

// ws byte offsets
#define OFF_NRM 0                // f32[8192]
#define OFF_XB  32768            // u16[8192*256] swizzled bf16 (4.19MB)

__device__ __forceinline__ unsigned short f2bf(float f) {
  unsigned u = __float_as_uint(f);
  return (unsigned short)((u + 0x7FFFu + ((u >> 16) & 1u)) >> 16);  // RNE
}

__device__ __forceinline__ unsigned umin32(unsigned a, unsigned b) { return a < b ? a : b; }
__device__ __forceinline__ unsigned umax32(unsigned a, unsigned b) { return a > b ? a : b; }

// ---------------------------------------------------------------- k_prep ----
// xb[(r,k)] stored at u16 index r*256 + ((k>>3) ^ (r&7))*8 + (k&7)
__global__ __launch_bounds__(256) void k_prep(const float* __restrict__ x,
                                              unsigned short* __restrict__ xb,
                                              float* __restrict__ nrm,
                                              float* __restrict__ out) {
  if (blockIdx.x == 0 && threadIdx.x == 0) out[0] = 0.0f;
  const int w = threadIdx.x >> 6, l = threadIdx.x & 63;
  const int r = blockIdx.x * 4 + w;
  const float4 xv = *reinterpret_cast<const float4*>(x + r * NK + l * 4);
  float ns = xv.x * xv.x + xv.y * xv.y + xv.z * xv.z + xv.w * xv.w;
  ns += __shfl_xor(ns, 1);  ns += __shfl_xor(ns, 2);  ns += __shfl_xor(ns, 4);
  ns += __shfl_xor(ns, 8);  ns += __shfl_xor(ns, 16); ns += __shfl_xor(ns, 32);
  if (l == 0) nrm[r] = ns;
  ushort4 bv;
  bv.x = f2bf(xv.x); bv.y = f2bf(xv.y); bv.z = f2bf(xv.z); bv.w = f2bf(xv.w);
  const int gs = (l >> 1) ^ (r & 7);
  *reinterpret_cast<ushort4*>(xb + r * NK + gs * 8 + (l & 1) * 4) = bv;
}

// ---------------------------------------------------------------- k_mega ----
// 256 blocks (1/CU) x 1024 thr (16 waves). Block = rows [rb*32, rb*32+32).
// Wave w sweeps 64-col tiles t = w + 16i (i=0..7).
__global__ __launch_bounds__(1024, 2) void k_mega(const unsigned short* __restrict__ xb,
                                                  const float* __restrict__ nrm,
                                                  const int* __restrict__ y,
                                                  float* __restrict__ out) {
  __shared__ float ncsAll[8192];      // all column norms (32KB)
  __shared__ float dpart[32];         // per-row denom
  __shared__ unsigned cl[32][512];    // per-row candidate lists (64KB)
  const int tid = threadIdx.x;
  const int w = tid >> 6, l = tid & 63, l15 = l & 15, l4 = l >> 4;
  const int rb = blockIdx.x;
  const int rowbase = rb * 32;

  #pragma unroll
  for (int j = 0; j < 8; ++j) ncsAll[tid + j * 1024] = nrm[tid + j * 1024];
  if (tid < 32) dpart[tid] = 0.0f;

  s8v A[2][8];  // the block's 32 rows x K=256, register-resident (per wave)
  #pragma unroll
  for (int rf = 0; rf < 2; ++rf) {
    const int rr = rowbase + rf * 16 + l15;
    #pragma unroll
    for (int kf = 0; kf < 8; ++kf) {
      const int g = ((kf << 2) | l4) ^ (rr & 7);
      A[rf][kf] = *reinterpret_cast<const s8v*>(xb + rr * NK + g * 8);
    }
  }
  float nr[2][4], dn[2][4];
  unsigned s0[2][4], s1[2][4];  // per-thread sorted top-2 keys per row
  #pragma unroll
  for (int rf = 0; rf < 2; ++rf)
    #pragma unroll
    for (int q = 0; q < 4; ++q) {
      nr[rf][q] = nrm[rowbase + rf * 16 + l4 * 4 + q];
      dn[rf][q] = 0.0f;
      s0[rf][q] = 0xFFFFFFFFu;
      s1[rf][q] = 0xFFFFFFFFu;
    }

  int koff[8];  // per-lane granule byte offset within a column's 512B row
  #pragma unroll
  for (int kf = 0; kf < 8; ++kf)
    koff[kf] = ((((kf << 2) | l4) ^ (l15 & 7)) << 4);
  const char* xbc = (const char*)xb;
  const int tdg = rb >> 1;            // tile containing this block's diagonal

  __syncthreads();                    // ncsAll/dpart published

  for (int i = 0; i < 8; ++i) {
    const int t = w + i * 16;
    const int cbase = t * 64;
    const char* bp = xbc + (size_t)(cbase + l15) * 512;
    f32x4 acc[2][4];
    #pragma unroll
    for (int cf = 0; cf < 4; ++cf) {
      f32x4 z = {0.f, 0.f, 0.f, 0.f};
      acc[0][cf] = z; acc[1][cf] = z;
    }
    #pragma unroll
    for (int kf = 0; kf < 8; ++kf) {
      const s8v b0 = *reinterpret_cast<const s8v*>(bp + koff[kf]);
      const s8v b1 = *reinterpret_cast<const s8v*>(bp + 8192 + koff[kf]);
      const s8v b2 = *reinterpret_cast<const s8v*>(bp + 16384 + koff[kf]);
      const s8v b3 = *reinterpret_cast<const s8v*>(bp + 24576 + koff[kf]);
      acc[0][0] = __builtin_amdgcn_mfma_f32_16x16x32_bf16(A[0][kf], b0, acc[0][0], 0, 0, 0);
      acc[1][0] = __builtin_amdgcn_mfma_f32_16x16x32_bf16(A[1][kf], b0, acc[1][0], 0, 0, 0);
      acc[0][1] = __builtin_amdgcn_mfma_f32_16x16x32_bf16(A[0][kf], b1, acc[0][1], 0, 0, 0);
      acc[1][1] = __builtin_amdgcn_mfma_f32_16x16x32_bf16(A[1][kf], b1, acc[1][1], 0, 0, 0);
      acc[0][2] = __builtin_amdgcn_mfma_f32_16x16x32_bf16(A[0][kf], b2, acc[0][2], 0, 0, 0);
      acc[1][2] = __builtin_amdgcn_mfma_f32_16x16x32_bf16(A[1][kf], b2, acc[1][2], 0, 0, 0);
      acc[0][3] = __builtin_amdgcn_mfma_f32_16x16x32_bf16(A[0][kf], b3, acc[0][3], 0, 0, 0);
      acc[1][3] = __builtin_amdgcn_mfma_f32_16x16x32_bf16(A[1][kf], b3, acc[1][3], 0, 0, 0);
    }
    float nc[4];
    #pragma unroll
    for (int cf = 0; cf < 4; ++cf) nc[cf] = ncsAll[cbase + cf * 16 + l15];
    auto epi = [&](auto dgc) {
      constexpr bool DG = decltype(dgc)::value;
      #pragma unroll
      for (int rf = 0; rf < 2; ++rf)
        #pragma unroll
        for (int cf = 0; cf < 4; ++cf) {
          const unsigned colg = (unsigned)(cbase + cf * 16 + l15);
          #pragma unroll
          for (int q = 0; q < 4; ++q) {
            const unsigned rowg = (unsigned)(rowbase + rf * 16 + l4 * 4 + q);
            float sq = fmaf(acc[rf][cf][q], -2.0f, nr[rf][q] + nc[cf]);
            if (DG) sq = fmaxf(sq, 0.0f);
            const float d = __builtin_amdgcn_sqrtf(sq);
            float e = __expf(-d);
            unsigned k = ((unsigned)__half_as_ushort(__float2half(d)) << 16) | colg;
            if (DG) {
              const bool nd = (rowg != colg);
              e = nd ? e : 0.0f;
              k = nd ? k : 0xFFFFFFFFu;
            }
            dn[rf][q] += e;
            const unsigned ev = umax32(s0[rf][q], k);
            s0[rf][q] = umin32(s0[rf][q], k);
            s1[rf][q] = umin32(s1[rf][q], ev);
          }
        }
    };
    if (t == tdg) epi(BoolC<true>{});
    else          epi(BoolC<false>{});
  }

  // ---- in-block merge (replaces k_fin) ----
  #pragma unroll
  for (int rf = 0; rf < 2; ++rf)
    #pragma unroll
    for (int q = 0; q < 4; ++q) {
      float vs = dn[rf][q];
      vs += __shfl_xor(vs, 1); vs += __shfl_xor(vs, 2);
      vs += __shfl_xor(vs, 4); vs += __shfl_xor(vs, 8);
      const int row32 = rf * 16 + l4 * 4 + q;
      if (l15 == 0) atomicAdd(&dpart[row32], vs);
      cl[row32][w * 32 + l15 * 2]     = s0[rf][q];
      cl[row32][w * 32 + l15 * 2 + 1] = s1[rf][q];
    }
  __syncthreads();

  float wsum = 0.0f;
  for (int rr = 0; rr < 2; ++rr) {   // wave w finalizes rows 2w, 2w+1
    const int row = w * 2 + rr;
    unsigned kk[8];
    #pragma unroll
    for (int j = 0; j < 8; ++j) kk[j] = cl[row][l * 8 + j];
    unsigned myKey = 0xFFFFFFFFu;
    for (int pp = 0; pp < 16; ++pp) {
      unsigned lm = kk[0];
      #pragma unroll
      for (int j = 1; j < 8; ++j) lm = umin32(lm, kk[j]);
      unsigned m = lm;
      m = umin32(m, __shfl_xor(m, 1));  m = umin32(m, __shfl_xor(m, 2));
      m = umin32(m, __shfl_xor(m, 4));  m = umin32(m, __shfl_xor(m, 8));
      m = umin32(m, __shfl_xor(m, 16)); m = umin32(m, __shfl_xor(m, 32));
      const unsigned long long bal = __ballot(lm == m);
      const int owner = (int)__ffsll(bal) - 1;
      if (l == owner) {
        bool f = false;
        #pragma unroll
        for (int j = 0; j < 8; ++j)
          if (!f && kk[j] == m) { kk[j] = 0xFFFFFFFFu; f = true; }
      }
      if (l == pp) myKey = m;
    }
    const float logden = __logf(dpart[row]);
    float contrib = 0.0f, cmf = 0.0f;
    if (l < 16 && myKey != 0xFFFFFFFFu) {
      const int col = (int)(myKey & 0x1FFFu);
      const float dd = __half2float(__ushort_as_half((unsigned short)(myKey >> 16)));
      if (y[col] == y[rowbase + row]) { contrib = -dd - logden; cmf = 1.0f; }
    }
    contrib += __shfl_xor(contrib, 1);  contrib += __shfl_xor(contrib, 2);
    contrib += __shfl_xor(contrib, 4);  contrib += __shfl_xor(contrib, 8);
    contrib += __shfl_xor(contrib, 16); contrib += __shfl_xor(contrib, 32);
    cmf += __shfl_xor(cmf, 1);  cmf += __shfl_xor(cmf, 2);
    cmf += __shfl_xor(cmf, 4);  cmf += __shfl_xor(cmf, 8);
    cmf += __shfl_xor(cmf, 16); cmf += __shfl_xor(cmf, 32);
    if (cmf > 0.0f) wsum += contrib / cmf;
  }
  if (l == 0) atomicAdd(out, wsum * (-1.0f / 8192.0f));
}

// ---------------------------------------------------------------------------
extern "C" void kernel_launch(void* const* d_in, const int* in_sizes, int n_in,
                              void* d_out, int out_size, void* d_ws, size_t ws_size,
                              hipStream_t stream) {
  const float* x = (const float*)d_in[0];
  const int* y = (const int*)d_in[1];
  float* out = (float*)d_out;
  char* ws = (char*)d_ws;

  float*          nrm = (float*)(ws + OFF_NRM);
  unsigned short* xb  = (unsigned short*)(ws + OFF_XB);

  k_prep<<<2048, 256,  0, stream>>>(x, xb, nrm, out);
  k_mega<<<256,  1024, 0, stream>>>(xb, nrm, y, out);
}

// Round 18
// 131.468 us; speedup vs baseline: 1.4257x; 1.4257x over previous
//
#include <hip/hip_runtime.h>
#include <hip/hip_fp16.h>

// ---------------------------------------------------------------------------
// ClassificationKNNLoss on MI355X — R18: R16 geometry + working VGPR bound.
//   k_prep : norms + bf16 convert with granule-XOR swizzle (+ zeroes d_out)
//   k_mega : 512 blocks (2/CU, 16 waves/CU) x 512 thr; block = 32 rows x
//            4096 cols. B direct from global; total B traffic = R13's 1.07GB.
//            Zero main-loop barriers/LDS. Per-block: per-row top-16 + denom
//            partial -> global.
//   k_fin  : merge 2 halves per row (32 keys), label match, loss.
// TOOLCHAIN LAW (R8..R17 measured): only (512,2) keeps VGPR cap 128; all
// (.,4) and ALL 1024-thr configs crush to 64 VGPR -> scratch spills.
// ---------------------------------------------------------------------------

typedef __attribute__((ext_vector_type(8))) short s8v;       // 8 x bf16 (4 VGPR)
typedef __attribute__((ext_vector_type(4))) float f32x4;     // MFMA acc

#define NK 256

template <bool B> struct BoolC { static constexpr bool value = B; };

// ws byte offsets
#define OFF_NRM 0                         // f32[8192] (32KB)
#define OFF_XB  32768                     // u16[8192*256] swizzled bf16 (4.19MB)
#define OFF_TOP (32768 + 4194304)         // u32[8192*2*16] per-half top16 (1MB)
#define OFF_DNP (OFF_TOP + 1048576)       // f32[8192*2] denom partials (64KB)

__device__ __forceinline__ unsigned short f2bf(float f) {
  unsigned u = __float_as_uint(f);
  return (unsigned short)((u + 0x7FFFu + ((u >> 16) & 1u)) >> 16);  // RNE
}

__device__ __forceinline__ unsigned umin32(unsigned a, unsigned b) { return a < b ? a : b; }
__device__ __forceinline__ unsigned umax32(unsigned a, unsigned b) { return a > b ? a : b; }

// ---------------------------------------------------------------- k_prep ----
// xb[(r,k)] stored at u16 index r*256 + ((k>>3) ^ (r&7))*8 + (k&7)
__global__ __launch_bounds__(256) void k_prep(const float* __restrict__ x,
                                              unsigned short* __restrict__ xb,
                                              float* __restrict__ nrm,
                                              float* __restrict__ out) {
  if (blockIdx.x == 0 && threadIdx.x == 0) out[0] = 0.0f;
  const int w = threadIdx.x >> 6, l = threadIdx.x & 63;
  const int r = blockIdx.x * 4 + w;
  const float4 xv = *reinterpret_cast<const float4*>(x + r * NK + l * 4);
  float ns = xv.x * xv.x + xv.y * xv.y + xv.z * xv.z + xv.w * xv.w;
  ns += __shfl_xor(ns, 1);  ns += __shfl_xor(ns, 2);  ns += __shfl_xor(ns, 4);
  ns += __shfl_xor(ns, 8);  ns += __shfl_xor(ns, 16); ns += __shfl_xor(ns, 32);
  if (l == 0) nrm[r] = ns;
  ushort4 bv;
  bv.x = f2bf(xv.x); bv.y = f2bf(xv.y); bv.z = f2bf(xv.z); bv.w = f2bf(xv.w);
  const int gs = (l >> 1) ^ (r & 7);
  *reinterpret_cast<ushort4*>(xb + r * NK + gs * 8 + (l & 1) * 4) = bv;
}

// ---------------------------------------------------------------- k_mega ----
// 512 blocks = 256 rb x 2 cs; 512 thr (8 waves); 32 rows x 4096 cols each.
// Wave w sweeps local tiles tl = w + 8i (i=0..7).
__global__ __launch_bounds__(512, 2) void k_mega(const unsigned short* __restrict__ xb,
                                                 const float* __restrict__ nrm,
                                                 unsigned* __restrict__ top16g,
                                                 float* __restrict__ dnpg) {
  __shared__ float ncsAll[4096];      // this half's column norms (16KB)
  __shared__ float dpart[32];         // per-row denom partial
  __shared__ unsigned cl[32][256];    // per-row candidate lists (32KB)
  const int tid = threadIdx.x;
  const int w = tid >> 6, l = tid & 63, l15 = l & 15, l4 = l >> 4;
  const int rb = blockIdx.x >> 1, cs = blockIdx.x & 1;
  const int rowbase = rb * 32;
  const int colbase = cs * 4096;

  #pragma unroll
  for (int j = 0; j < 8; ++j) ncsAll[tid + j * 512] = nrm[colbase + tid + j * 512];
  if (tid < 32) dpart[tid] = 0.0f;

  s8v A[2][8];  // the block's 32 rows x K=256, register-resident
  #pragma unroll
  for (int rf = 0; rf < 2; ++rf) {
    const int rr = rowbase + rf * 16 + l15;
    #pragma unroll
    for (int kf = 0; kf < 8; ++kf) {
      const int g = ((kf << 2) | l4) ^ (rr & 7);
      A[rf][kf] = *reinterpret_cast<const s8v*>(xb + rr * NK + g * 8);
    }
  }
  float nr[2][4], dn[2][4];
  unsigned s0[2][4], s1[2][4];  // per-thread sorted top-2 keys per row
  #pragma unroll
  for (int rf = 0; rf < 2; ++rf)
    #pragma unroll
    for (int q = 0; q < 4; ++q) {
      nr[rf][q] = nrm[rowbase + rf * 16 + l4 * 4 + q];
      dn[rf][q] = 0.0f;
      s0[rf][q] = 0xFFFFFFFFu;
      s1[rf][q] = 0xFFFFFFFFu;
    }

  int koff[8];  // per-lane granule byte offset within a column's 512B row
  #pragma unroll
  for (int kf = 0; kf < 8; ++kf)
    koff[kf] = ((((kf << 2) | l4) ^ (l15 & 7)) << 4);
  const char* xbc = (const char*)xb;
  const int tdg = rb >> 1;            // GLOBAL tile containing the diagonal

  __syncthreads();                    // ncsAll/dpart published

  for (int i = 0; i < 8; ++i) {
    const int tl = w + i * 8;         // local tile in this half
    const int t = cs * 64 + tl;       // global tile
    const int cbase = t * 64;
    const char* bp = xbc + (size_t)(cbase + l15) * 512;
    f32x4 acc[2][4];
    #pragma unroll
    for (int cf = 0; cf < 4; ++cf) {
      f32x4 z = {0.f, 0.f, 0.f, 0.f};
      acc[0][cf] = z; acc[1][cf] = z;
    }
    #pragma unroll
    for (int kf = 0; kf < 8; ++kf) {
      const s8v b0 = *reinterpret_cast<const s8v*>(bp + koff[kf]);
      const s8v b1 = *reinterpret_cast<const s8v*>(bp + 8192 + koff[kf]);
      const s8v b2 = *reinterpret_cast<const s8v*>(bp + 16384 + koff[kf]);
      const s8v b3 = *reinterpret_cast<const s8v*>(bp + 24576 + koff[kf]);
      acc[0][0] = __builtin_amdgcn_mfma_f32_16x16x32_bf16(A[0][kf], b0, acc[0][0], 0, 0, 0);
      acc[1][0] = __builtin_amdgcn_mfma_f32_16x16x32_bf16(A[1][kf], b0, acc[1][0], 0, 0, 0);
      acc[0][1] = __builtin_amdgcn_mfma_f32_16x16x32_bf16(A[0][kf], b1, acc[0][1], 0, 0, 0);
      acc[1][1] = __builtin_amdgcn_mfma_f32_16x16x32_bf16(A[1][kf], b1, acc[1][1], 0, 0, 0);
      acc[0][2] = __builtin_amdgcn_mfma_f32_16x16x32_bf16(A[0][kf], b2, acc[0][2], 0, 0, 0);
      acc[1][2] = __builtin_amdgcn_mfma_f32_16x16x32_bf16(A[1][kf], b2, acc[1][2], 0, 0, 0);
      acc[0][3] = __builtin_amdgcn_mfma_f32_16x16x32_bf16(A[0][kf], b3, acc[0][3], 0, 0, 0);
      acc[1][3] = __builtin_amdgcn_mfma_f32_16x16x32_bf16(A[1][kf], b3, acc[1][3], 0, 0, 0);
    }
    float nc[4];
    #pragma unroll
    for (int cf = 0; cf < 4; ++cf) nc[cf] = ncsAll[tl * 64 + cf * 16 + l15];
    auto epi = [&](auto dgc) {
      constexpr bool DG = decltype(dgc)::value;
      #pragma unroll
      for (int rf = 0; rf < 2; ++rf)
        #pragma unroll
        for (int cf = 0; cf < 4; ++cf) {
          const unsigned colg = (unsigned)(cbase + cf * 16 + l15);
          #pragma unroll
          for (int q = 0; q < 4; ++q) {
            const unsigned rowg = (unsigned)(rowbase + rf * 16 + l4 * 4 + q);
            float sq = fmaf(acc[rf][cf][q], -2.0f, nr[rf][q] + nc[cf]);
            if (DG) sq = fmaxf(sq, 0.0f);
            const float d = __builtin_amdgcn_sqrtf(sq);
            float e = __expf(-d);
            unsigned k = ((unsigned)__half_as_ushort(__float2half(d)) << 16) | colg;
            if (DG) {
              const bool nd = (rowg != colg);
              e = nd ? e : 0.0f;
              k = nd ? k : 0xFFFFFFFFu;
            }
            dn[rf][q] += e;
            const unsigned ev = umax32(s0[rf][q], k);
            s0[rf][q] = umin32(s0[rf][q], k);
            s1[rf][q] = umin32(s1[rf][q], ev);
          }
        }
    };
    if (t == tdg) epi(BoolC<true>{});
    else          epi(BoolC<false>{});
  }

  // ---- in-block reduce to per-row top-16 + denom partial ----
  #pragma unroll
  for (int rf = 0; rf < 2; ++rf)
    #pragma unroll
    for (int q = 0; q < 4; ++q) {
      float vs = dn[rf][q];
      vs += __shfl_xor(vs, 1); vs += __shfl_xor(vs, 2);
      vs += __shfl_xor(vs, 4); vs += __shfl_xor(vs, 8);
      const int row32 = rf * 16 + l4 * 4 + q;
      if (l15 == 0) atomicAdd(&dpart[row32], vs);
      cl[row32][w * 32 + l15 * 2]     = s0[rf][q];
      cl[row32][w * 32 + l15 * 2 + 1] = s1[rf][q];
    }
  __syncthreads();

  for (int rr = 0; rr < 4; ++rr) {   // wave w reduces rows 4w..4w+3
    const int row = w * 4 + rr;
    unsigned kk[4];
    #pragma unroll
    for (int j = 0; j < 4; ++j) kk[j] = cl[row][l * 4 + j];
    unsigned myKey = 0xFFFFFFFFu;
    for (int pp = 0; pp < 16; ++pp) {
      const unsigned lm = umin32(umin32(kk[0], kk[1]), umin32(kk[2], kk[3]));
      unsigned m = lm;
      m = umin32(m, __shfl_xor(m, 1));  m = umin32(m, __shfl_xor(m, 2));
      m = umin32(m, __shfl_xor(m, 4));  m = umin32(m, __shfl_xor(m, 8));
      m = umin32(m, __shfl_xor(m, 16)); m = umin32(m, __shfl_xor(m, 32));
      const unsigned long long bal = __ballot(lm == m);
      const int owner = (int)__ffsll(bal) - 1;
      if (l == owner) {
        bool f = false;
        #pragma unroll
        for (int j = 0; j < 4; ++j)
          if (!f && kk[j] == m) { kk[j] = 0xFFFFFFFFu; f = true; }
      }
      if (l == pp) myKey = m;
    }
    const int rowg = rowbase + row;
    if (l < 16) top16g[(rowg * 2 + cs) * 16 + l] = myKey;
    if (l == 16) dnpg[rowg * 2 + cs] = dpart[row];
  }
}

// ----------------------------------------------------------------- k_fin ----
// Merge the two 16-candidate halves per row; label match; loss.
__global__ __launch_bounds__(256) void k_fin(const unsigned* __restrict__ top16g,
                                             const float* __restrict__ dnpg,
                                             const int* __restrict__ y,
                                             float* __restrict__ out) {
  const int w = threadIdx.x >> 6, l = threadIdx.x & 63;
  const int r = blockIdx.x * 4 + w;
  unsigned kk = (l < 32) ? top16g[r * 32 + l] : 0xFFFFFFFFu;
  unsigned myKey = 0xFFFFFFFFu;
  for (int pp = 0; pp < 16; ++pp) {
    unsigned m = kk;
    m = umin32(m, __shfl_xor(m, 1));  m = umin32(m, __shfl_xor(m, 2));
    m = umin32(m, __shfl_xor(m, 4));  m = umin32(m, __shfl_xor(m, 8));
    m = umin32(m, __shfl_xor(m, 16)); m = umin32(m, __shfl_xor(m, 32));
    const unsigned long long bal = __ballot(kk == m);
    const int owner = (int)__ffsll(bal) - 1;
    if (l == owner) kk = 0xFFFFFFFFu;
    if (l == pp) myKey = m;
  }
  const float den = dnpg[r * 2] + dnpg[r * 2 + 1];
  const float logden = __logf(den);
  float contrib = 0.0f, cmf = 0.0f;
  if (l < 16 && myKey != 0xFFFFFFFFu) {
    const int col = (int)(myKey & 0x1FFFu);
    const float dd = __half2float(__ushort_as_half((unsigned short)(myKey >> 16)));
    if (y[col] == y[r]) { contrib = -dd - logden; cmf = 1.0f; }
  }
  contrib += __shfl_xor(contrib, 1);  contrib += __shfl_xor(contrib, 2);
  contrib += __shfl_xor(contrib, 4);  contrib += __shfl_xor(contrib, 8);
  contrib += __shfl_xor(contrib, 16); contrib += __shfl_xor(contrib, 32);
  cmf += __shfl_xor(cmf, 1);  cmf += __shfl_xor(cmf, 2);
  cmf += __shfl_xor(cmf, 4);  cmf += __shfl_xor(cmf, 8);
  cmf += __shfl_xor(cmf, 16); cmf += __shfl_xor(cmf, 32);
  if (l == 0 && cmf > 0.0f)
    atomicAdd(out, (contrib / cmf) * (-1.0f / 8192.0f));
}

// ---------------------------------------------------------------------------
extern "C" void kernel_launch(void* const* d_in, const int* in_sizes, int n_in,
                              void* d_out, int out_size, void* d_ws, size_t ws_size,
                              hipStream_t stream) {
  const float* x = (const float*)d_in[0];
  const int* y = (const int*)d_in[1];
  float* out = (float*)d_out;
  char* ws = (char*)d_ws;

  float*          nrm    = (float*)(ws + OFF_NRM);
  unsigned short* xb     = (unsigned short*)(ws + OFF_XB);
  unsigned*       top16g = (unsigned*)(ws + OFF_TOP);
  float*          dnpg   = (float*)(ws + OFF_DNP);

  k_prep<<<2048, 256, 0, stream>>>(x, xb, nrm, out);
  k_mega<<<512,  512, 0, stream>>>(xb, nrm, top16g, dnpg);
  k_fin <<<2048, 256, 0, stream>>>(top16g, dnpg, y, out);
}